// Round 7
// baseline (158.329 us; speedup 1.0000x reference)
//
#include <hip/hip_runtime.h>

typedef unsigned short u16;
typedef unsigned int u32;
typedef __bf16 bf16x8 __attribute__((ext_vector_type(8)));
typedef float f32x4 __attribute__((ext_vector_type(4)));

#define SEQ 2048
#define DMODEL 1024
#define NH 16
#define DK 64
#define BATCH 2
#define MTOT (BATCH * SEQ) // 4096

__device__ __forceinline__ u16 f2b(float f) {
  u32 u = __float_as_uint(f);
  u += 0x7fffu + ((u >> 16) & 1u);
  return (u16)(u >> 16);
}

__device__ __forceinline__ void gload16(const void* g, void* l) {
  __builtin_amdgcn_global_load_lds((const __attribute__((address_space(1))) u32*)g,
                                   (__attribute__((address_space(3))) u32*)l, 16, 0, 0);
}

// ---------------- fp32 -> bf16 convert (vectorized) ----------------
__global__ __launch_bounds__(256) void cvt_bf16(const float* __restrict__ in,
                                                u16* __restrict__ out, int n4) {
  int i = blockIdx.x * 256 + threadIdx.x;
  if (i < n4) {
    float4 v = ((const float4*)in)[i];
    uint2 o;
    o.x = (u32)f2b(v.x) | ((u32)f2b(v.y) << 16);
    o.y = (u32)f2b(v.z) | ((u32)f2b(v.w) << 16);
    ((uint2*)out)[i] = o;
  }
}

// ---------------- 3 weight matrices in one launch: grid (1024, 3) ----------------
__global__ __launch_bounds__(256) void cvt_w3(const float* __restrict__ wq,
                                              const float* __restrict__ wk,
                                              const float* __restrict__ wv,
                                              u16* __restrict__ oq,
                                              u16* __restrict__ ok,
                                              u16* __restrict__ ov) {
  const int m = blockIdx.y;
  const float* in = (m == 0) ? wq : ((m == 1) ? wk : wv);
  u16* out = (m == 0) ? oq : ((m == 1) ? ok : ov);
  const int i = blockIdx.x * 256 + threadIdx.x; // < DMODEL*DMODEL/4
  float4 v = ((const float4*)in)[i];
  uint2 o;
  o.x = (u32)f2b(v.x) | ((u32)f2b(v.y) << 16);
  o.y = (u32)f2b(v.z) | ((u32)f2b(v.w) << 16);
  ((uint2*)out)[i] = o;
}

// ---------------- RoPE cos/sin table: tab[s*32+Xi] = (cos, sin) ----------------
__global__ __launch_bounds__(256) void rope_tab_k(const int* __restrict__ tokpos,
                                                  float2* __restrict__ tab) {
  const int i = blockIdx.x * 256 + threadIdx.x; // < SEQ*32
  const int s = i >> 5, Xi = i & 31;
  const float invf = powf(1000.0f, -(float)Xi / 32.0f);
  const float ang = (float)tokpos[s] * invf;
  float sn, cs;
  sincosf(ang, &sn, &cs);
  tab[i] = make_float2(cs, sn);
}

// ---------------- Wo transpose + convert: wot[e][d] = wo[d][e] ----------------
__global__ __launch_bounds__(256) void transpose_wo(const float* __restrict__ wo,
                                                    u16* __restrict__ wot) {
  __shared__ float tile[32][33];
  const int bx = blockIdx.x * 32; // e block
  const int by = blockIdx.y * 32; // d block
  const int tx = threadIdx.x & 31, ty = threadIdx.x >> 5;
  for (int j = ty; j < 32; j += 8)
    tile[j][tx] = wo[(size_t)(by + j) * DMODEL + bx + tx];
  __syncthreads();
  for (int j = ty; j < 32; j += 8)
    wot[(size_t)(bx + j) * DMODEL + by + tx] = f2b(tile[tx][j]);
}

// ---------------- shared GEMM mainloop (BK=32, 2-phase dbuf, XOR swizzle) --------
// C[BM x 128] = A[M,K] * Bt[N,K]^T, BM = MI*32. 4 waves: wr = w>>1 (BM/2 rows),
// wc = w&1 (64 cols). Double-buffered 32KB-class LDS: prefetch for tile t+1 issued
// right after the single per-iteration barrier, flying during tile t's compute,
// drained by the next barrier. Chunk swizzle: LDS[row][c] = G[row][c ^ f(row)],
// f(row) = (row&3)^((row>>2)&3) (16B chunks); reads apply the same XOR.
template <int MI>
__device__ __forceinline__ void gemm_core(const u16* __restrict__ A,
                                          const u16* __restrict__ Bt,
                                          int mbase, int nbase,
                                          u16* As, u16* Bs, f32x4 acc[MI][4]) {
  const int t = threadIdx.x;
  const int lane = t & 63, w = t >> 6;
  const int wr = w >> 1, wc = w & 1;
  const int l15 = lane & 15, lg = lane >> 4;
  const int srow = t >> 2;                                    // 0..63
  const int sch = (t & 3) ^ (srow & 3) ^ ((srow >> 2) & 3);   // swizzled source chunk
  const int rsw = (l15 & 3) ^ ((l15 >> 2) & 3);               // read-side XOR
  const int ASZ = MI * 1024; // elems per A buffer (MI*32 rows x 32)
  const int BSZ = 4096;      // 128 x 32
  const int ASETS = MI / 2;

  // prologue: stage tile 0 into buf 0
#pragma unroll
  for (int j = 0; j < ASETS; ++j)
    gload16(&A[(size_t)(mbase + j * 64 + srow) * DMODEL + sch * 8], &As[j * 2048 + t * 8]);
#pragma unroll
  for (int j = 0; j < 2; ++j)
    gload16(&Bt[(size_t)(nbase + j * 64 + srow) * DMODEL + sch * 8], &Bs[j * 2048 + t * 8]);

  for (int it = 0; it < DMODEL / 32; ++it) {
    const int buf = it & 1;
    __syncthreads(); // tile `it` landed; previous iteration's LDS reads done
    if (it + 1 < DMODEL / 32) {
      const int kb = (it + 1) * 32;
      u16* Ad = &As[(buf ^ 1) * ASZ];
      u16* Bd = &Bs[(buf ^ 1) * BSZ];
#pragma unroll
      for (int j = 0; j < ASETS; ++j)
        gload16(&A[(size_t)(mbase + j * 64 + srow) * DMODEL + kb + sch * 8],
                &Ad[j * 2048 + t * 8]);
#pragma unroll
      for (int j = 0; j < 2; ++j)
        gload16(&Bt[(size_t)(nbase + j * 64 + srow) * DMODEL + kb + sch * 8],
                &Bd[j * 2048 + t * 8]);
    }
    const u16* Ac = &As[buf * ASZ];
    const u16* Bc = &Bs[buf * BSZ];
    bf16x8 af[MI], bfr[4];
#pragma unroll
    for (int mi = 0; mi < MI; ++mi) {
      const int row = wr * (MI * 16) + mi * 16 + l15;
      af[mi] = *(const bf16x8*)&Ac[row * 32 + ((lg ^ rsw) * 8)];
    }
#pragma unroll
    for (int ni = 0; ni < 4; ++ni) {
      const int row = wc * 64 + ni * 16 + l15;
      bfr[ni] = *(const bf16x8*)&Bc[row * 32 + ((lg ^ rsw) * 8)];
    }
#pragma unroll
    for (int mi = 0; mi < MI; ++mi)
#pragma unroll
      for (int ni = 0; ni < 4; ++ni)
        acc[mi][ni] =
            __builtin_amdgcn_mfma_f32_16x16x32_bf16(af[mi], bfr[ni], acc[mi][ni], 0, 0, 0);
  }
}

// ---------------- fused QKV projection + RoPE epilogue (table-based) ----------------
// Q gets 0.125*log2(e) folded in (attention scale + exp2-domain softmax).
// V is written TRANSPOSED per head: Vb[(bh*DK + vd)*SEQ + s].
__global__ __launch_bounds__(256) void gemm_qkv(
    const u16* __restrict__ Xb, const u16* __restrict__ Wqb,
    const u16* __restrict__ Wkb, const u16* __restrict__ Wvb,
    u16* __restrict__ Qb, u16* __restrict__ Kb, u16* __restrict__ Vb,
    const float2* __restrict__ tab) {
  __shared__ __align__(16) u16 As[2 * 128 * 32]; // 16 KB
  __shared__ __align__(16) u16 Bs[2 * 128 * 32]; // 16 KB

  const int mat = blockIdx.y >> 3;
  const int nbase = (blockIdx.y & 7) * 128;
  const int mbase = blockIdx.x * 128;
  const u16* Bt = (mat == 0) ? Wqb : ((mat == 1) ? Wkb : Wvb);

  f32x4 acc[4][4];
#pragma unroll
  for (int mi = 0; mi < 4; ++mi)
#pragma unroll
    for (int ni = 0; ni < 4; ++ni) {
      f32x4 z = {0.f, 0.f, 0.f, 0.f};
      acc[mi][ni] = z;
    }

  gemm_core<4>(Xb, Bt, mbase, nbase, As, Bs, acc);

  const int t = threadIdx.x;
  const int lane = t & 63, w = t >> 6;
  const int wr = w >> 1, wc = w & 1;
  const int l15 = lane & 15, lg = lane >> 4;

  if (mat == 2) { // V: no rope, write V^T per head [B,H,64,S]
#pragma unroll
    for (int mi = 0; mi < 4; ++mi) {
#pragma unroll
      for (int r = 0; r < 4; ++r) {
        const int row = mbase + wr * 64 + mi * 16 + lg * 4 + r;
        const int bi = row >> 11, s = row & (SEQ - 1);
#pragma unroll
        for (int ni = 0; ni < 4; ++ni) {
          const int c = nbase + wc * 64 + ni * 16 + l15;
          const int hh = c & 15, vd = c >> 4;
          Vb[((size_t)((bi * NH + hh) * DK + vd)) * SEQ + s] = f2b(acc[mi][ni][r]);
        }
      }
    }
  } else { // Q or K: rope on (ni, ni+1) pairs, cos/sin from table
    u16* Ob = (mat == 0) ? Qb : Kb;
    const float qscale = (mat == 0) ? 0.125f * 1.44269504088896f : 1.0f;
#pragma unroll
    for (int ni = 0; ni < 4; ni += 2) {
      const int Xi = (nbase + wc * 64 + ni * 16) >> 5; // 0..31, uniform per frag
#pragma unroll
      for (int mi = 0; mi < 4; ++mi) {
#pragma unroll
        for (int r = 0; r < 4; ++r) {
          const int row = mbase + wr * 64 + mi * 16 + lg * 4 + r;
          const int bi = row >> 11, s = row & (SEQ - 1);
          const float2 ct = tab[(s << 5) + Xi]; // broadcast across 16 lanes
          const float x1 = acc[mi][ni][r], x2 = acc[mi][ni + 1][r];
          const float r1 = (x1 * ct.x - x2 * ct.y) * qscale;
          const float r2 = (x1 * ct.y + x2 * ct.x) * qscale;
          const u32 pk = (u32)f2b(r1) | ((u32)f2b(r2) << 16);
          *(u32*)&Ob[((size_t)((bi * NH + l15) * SEQ + s) << 6) + (Xi << 1)] = pk;
        }
      }
    }
  }
}

// ---------------- flash attention (causal, swapped-operand, in-register softmax) ---
// grid 1024 blocks = 32 q-tiles x 32 heads, remapped so each XCD owns 4 heads
// (KV L2-resident) and heavy q-tiles dispatch first. 256 thr = 4 waves; wave owns
// 16 q rows (q = lane&15 after swapped QK^T -> softmax is lane-local scalars).
// KV tile 64, double-buffered global_load_lds with XOR chunk swizzle.
__global__ __launch_bounds__(256) void flash_attn(
    const u16* __restrict__ Qg, const u16* __restrict__ Kg,
    const u16* __restrict__ VTg, u16* __restrict__ Ag) {
  __shared__ __align__(16) u16 Ks[2][64 * 64];
  __shared__ __align__(16) u16 Vs[2][64 * 64];
  __shared__ __align__(16) u16 Ps[4][16][72];

  // work-id swizzle: id&7 -> XCD slot, 4 heads per XCD, qt descending (heavy first)
  const int id = blockIdx.y * 32 + blockIdx.x;
  const int within = id >> 3;
  const int bh = (id & 7) * 4 + (within & 3);
  const int qt = 31 - (within >> 2);
  const int b = bh >> 4, h = bh & 15;
  const int qbase = qt * 64;

  const size_t hoff = (size_t)bh * SEQ * DK;
  const u16* Qh = Qg + hoff;
  const u16* Kh = Kg + hoff;
  const u16* VTh = VTg + hoff;

  const int t = threadIdx.x;
  const int lane = t & 63, w = t >> 6;
  const int l15 = lane & 15, lg = lane >> 4;
  const int sw = l15 & 7; // read-side XOR

  const int qrow = qbase + w * 16 + l15; // this lane's q row
  const bf16x8 qf0 = *(const bf16x8*)&Qh[(size_t)qrow * DK + lg * 8];
  const bf16x8 qf1 = *(const bf16x8*)&Qh[(size_t)qrow * DK + 32 + lg * 8];

  f32x4 oaccT[4]; // O^T[v = vf*16+lg*4+r][q = l15]
#pragma unroll
  for (int vf = 0; vf < 4; ++vf) {
    f32x4 z = {0.f, 0.f, 0.f, 0.f};
    oaccT[vf] = z;
  }
  float m_r = -1e30f, l_r = 0.0f; // per-lane (per q-row) softmax state

  // staging map: thread t covers LDS bytes [t*16) and [4096 + t*16)
  const int srow = t >> 3;                     // 0..31
  const int sc = ((t & 7) ^ (srow & 7)) * 8;   // swizzled global source chunk

  // prologue: stage tile 0 into buf 0
  gload16(&Kh[(size_t)srow * DK + sc], &Ks[0][t * 8]);
  gload16(&Kh[(size_t)(srow + 32) * DK + sc], &Ks[0][2048 + t * 8]);
  gload16(&VTh[(size_t)srow * SEQ + sc], &Vs[0][t * 8]);
  gload16(&VTh[(size_t)(srow + 32) * SEQ + sc], &Vs[0][2048 + t * 8]);

  for (int kt = 0; kt <= qt; ++kt) {
    const int buf = kt & 1;
    __syncthreads(); // tile kt landed; previous iteration's LDS reads done
    if (kt < qt) {
      const int kb = (kt + 1) * 64;
      gload16(&Kh[(size_t)(kb + srow) * DK + sc], &Ks[buf ^ 1][t * 8]);
      gload16(&Kh[(size_t)(kb + srow + 32) * DK + sc], &Ks[buf ^ 1][2048 + t * 8]);
      gload16(&VTh[(size_t)srow * SEQ + kb + sc], &Vs[buf ^ 1][t * 8]);
      gload16(&VTh[(size_t)(srow + 32) * SEQ + kb + sc], &Vs[buf ^ 1][2048 + t * 8]);
    }
    const int kvbase = kt * 64;

    // S^T = K Q^T : lane holds S[q=qrow][kv = kvbase + f*16 + lg*4 + r]
    f32x4 sT[4];
#pragma unroll
    for (int f = 0; f < 4; ++f) {
      const int row = f * 16 + l15;
      bf16x8 k0 = *(const bf16x8*)&Ks[buf][row * 64 + (lg ^ sw) * 8];
      bf16x8 k1 = *(const bf16x8*)&Ks[buf][row * 64 + ((4 + lg) ^ sw) * 8];
      f32x4 z = {0.f, 0.f, 0.f, 0.f};
      z = __builtin_amdgcn_mfma_f32_16x16x32_bf16(k0, qf0, z, 0, 0, 0);
      z = __builtin_amdgcn_mfma_f32_16x16x32_bf16(k1, qf1, z, 0, 0, 0);
      sT[f] = z;
    }

    if (kt == qt) { // only the diagonal tile needs masking
#pragma unroll
      for (int f = 0; f < 4; ++f)
#pragma unroll
        for (int r = 0; r < 4; ++r) {
          const int kvc = kvbase + f * 16 + lg * 4 + r;
          if (kvc > qrow) sT[f][r] = -1e30f;
        }
    }

    // in-lane row max (16 vals) + 2 cross-lane steps (lg dimension)
    f32x4 mv;
#pragma unroll
    for (int r = 0; r < 4; ++r)
      mv[r] = fmaxf(fmaxf(sT[0][r], sT[1][r]), fmaxf(sT[2][r], sT[3][r]));
    float mx = fmaxf(fmaxf(mv[0], mv[1]), fmaxf(mv[2], mv[3]));
    mx = fmaxf(mx, __shfl_xor(mx, 16));
    mx = fmaxf(mx, __shfl_xor(mx, 32));

    const float mn = fmaxf(m_r, mx);
    const float alpha = exp2f(m_r - mn);
    m_r = mn;
#pragma unroll
    for (int f = 0; f < 4; ++f)
#pragma unroll
      for (int r = 0; r < 4; ++r) sT[f][r] = exp2f(sT[f][r] - mn);

    f32x4 rv;
#pragma unroll
    for (int r = 0; r < 4; ++r) rv[r] = (sT[0][r] + sT[1][r]) + (sT[2][r] + sT[3][r]);
    float rs = (rv[0] + rv[1]) + (rv[2] + rv[3]);
    rs += __shfl_xor(rs, 16);
    rs += __shfl_xor(rs, 32);
    l_r = l_r * alpha + rs;

#pragma unroll
    for (int vf = 0; vf < 4; ++vf)
#pragma unroll
      for (int r = 0; r < 4; ++r) oaccT[vf][r] *= alpha;

    // P row (q=l15) -> LDS: 4x ds_write_b64, contiguous kv runs
#pragma unroll
    for (int f = 0; f < 4; ++f) {
      uint2 pkv;
      pkv.x = (u32)f2b(sT[f][0]) | ((u32)f2b(sT[f][1]) << 16);
      pkv.y = (u32)f2b(sT[f][2]) | ((u32)f2b(sT[f][3]) << 16);
      *(uint2*)&Ps[w][l15][f * 16 + lg * 4] = pkv;
    }

    // O^T += V^T P^T : A = V^T frag, B = P^T frag (2x ds_read_b128 for P)
#pragma unroll
    for (int c = 0; c < 2; ++c) {
      const bf16x8 pb = *(const bf16x8*)&Ps[w][l15][c * 32 + lg * 8];
#pragma unroll
      for (int vf = 0; vf < 4; ++vf) {
        const bf16x8 va =
            *(const bf16x8*)&Vs[buf][(vf * 16 + l15) * 64 + ((c * 4 + lg) ^ sw) * 8];
        oaccT[vf] = __builtin_amdgcn_mfma_f32_16x16x32_bf16(va, pb, oaccT[vf], 0, 0, 0);
      }
    }
  }

  // normalize + write [B,S,D] bf16: d = h*64 + v, packed 4-wide
  const float inv = 1.0f / l_r;
  const size_t base = ((size_t)(b * SEQ + qrow)) * DMODEL + h * DK;
#pragma unroll
  for (int vf = 0; vf < 4; ++vf) {
    uint2 ov;
    ov.x = (u32)f2b(oaccT[vf][0] * inv) | ((u32)f2b(oaccT[vf][1] * inv) << 16);
    ov.y = (u32)f2b(oaccT[vf][2] * inv) | ((u32)f2b(oaccT[vf][3] * inv) << 16);
    *(uint2*)&Ag[base + vf * 16 + lg * 4] = ov;
  }
}

// ---------------- output projection: d_out = Ab * Wot^T (fp32 out) ----------------
// 64x128 tile (MI=2), grid (64, 8) = 512 blocks, all resident (2/CU).
__global__ __launch_bounds__(256) void gemm_out(const u16* __restrict__ Ab,
                                                const u16* __restrict__ Wotb,
                                                float* __restrict__ Co) {
  __shared__ __align__(16) u16 As[2 * 64 * 32];  // 8 KB
  __shared__ __align__(16) u16 Bs[2 * 128 * 32]; // 16 KB
  const int mbase = blockIdx.x * 64, nbase = blockIdx.y * 128;

  f32x4 acc[2][4];
#pragma unroll
  for (int mi = 0; mi < 2; ++mi)
#pragma unroll
    for (int ni = 0; ni < 4; ++ni) {
      f32x4 z = {0.f, 0.f, 0.f, 0.f};
      acc[mi][ni] = z;
    }

  gemm_core<2>(Ab, Wotb, mbase, nbase, As, Bs, acc);

  const int t = threadIdx.x;
  const int lane = t & 63, w = t >> 6;
  const int wr = w >> 1, wc = w & 1;
  const int l15 = lane & 15, lg = lane >> 4;
#pragma unroll
  for (int mi = 0; mi < 2; ++mi) {
#pragma unroll
    for (int r = 0; r < 4; ++r) {
      const int row = mbase + wr * 32 + mi * 16 + lg * 4 + r;
#pragma unroll
      for (int ni = 0; ni < 4; ++ni) {
        const int c = nbase + wc * 64 + ni * 16 + l15;
        Co[(size_t)row * DMODEL + c] = acc[mi][ni][r];
      }
    }
  }
}

extern "C" void kernel_launch(void* const* d_in, const int* in_sizes, int n_in,
                              void* d_out, int out_size, void* d_ws, size_t ws_size,
                              hipStream_t stream) {
  const float* X = (const float*)d_in[0];
  const float* Wq = (const float*)d_in[1];
  const float* Wk = (const float*)d_in[2];
  const float* Wv = (const float*)d_in[3];
  const float* Wo = (const float*)d_in[4];
  const int* tokpos = (const int*)d_in[5];
  float* out = (float*)d_out;

  u16* p = (u16*)d_ws;
  u16* Xb = p;   p += (size_t)MTOT * DMODEL;        // 4M el
  u16* Wqb = p;  p += (size_t)DMODEL * DMODEL;      // 1M el
  u16* Wkb = p;  p += (size_t)DMODEL * DMODEL;
  u16* Wvb = p;  p += (size_t)DMODEL * DMODEL;
  u16* Wotb = p; p += (size_t)DMODEL * DMODEL;
  u16* Qb = p;   p += (size_t)BATCH * NH * SEQ * DK; // 4M el
  u16* Kb = p;   p += (size_t)BATCH * NH * SEQ * DK;
  u16* Vb = p;   p += (size_t)BATCH * NH * SEQ * DK; // holds V^T [bh][vd][s]
  float2* tab = (float2*)(p + 512);                  // 512 KB rope table (aligned)
  u16* Ab = Xb; // X is dead after QKV projection; reuse for attention output

  cvt_bf16<<<4096, 256, 0, stream>>>(X, Xb, (MTOT * DMODEL) / 4);
  cvt_w3<<<dim3(1024, 3), 256, 0, stream>>>(Wq, Wk, Wv, Wqb, Wkb, Wvb);
  transpose_wo<<<dim3(32, 32), 256, 0, stream>>>(Wo, Wotb);
  rope_tab_k<<<(SEQ * 32) / 256, 256, 0, stream>>>(tokpos, tab);

  gemm_qkv<<<dim3(32, 24), 256, 0, stream>>>(Xb, Wqb, Wkb, Wvb, Qb, Kb, Vb, tab);
  flash_attn<<<dim3(32, 32), 256, 0, stream>>>(Qb, Kb, Vb, Ab);
  gemm_out<<<dim3(64, 8), 256, 0, stream>>>(Ab, Wotb, out);
}

// Round 8
// 140.600 us; speedup vs baseline: 1.1261x; 1.1261x over previous
//
#include <hip/hip_runtime.h>

typedef unsigned short u16;
typedef unsigned int u32;
typedef __bf16 bf16x8 __attribute__((ext_vector_type(8)));
typedef float f32x4 __attribute__((ext_vector_type(4)));

#define SEQ 2048
#define DMODEL 1024
#define NH 16
#define DK 64
#define BATCH 2
#define MTOT (BATCH * SEQ) // 4096

__device__ __forceinline__ u16 f2b(float f) {
  u32 u = __float_as_uint(f);
  u += 0x7fffu + ((u >> 16) & 1u);
  return (u16)(u >> 16);
}

__device__ __forceinline__ void gload16(const void* g, void* l) {
  __builtin_amdgcn_global_load_lds((const __attribute__((address_space(1))) u32*)g,
                                   (__attribute__((address_space(3))) u32*)l, 16, 0, 0);
}

// ---------------- fp32 -> bf16 convert (vectorized) ----------------
__global__ __launch_bounds__(256) void cvt_bf16(const float* __restrict__ in,
                                                u16* __restrict__ out, int n4) {
  int i = blockIdx.x * 256 + threadIdx.x;
  if (i < n4) {
    float4 v = ((const float4*)in)[i];
    uint2 o;
    o.x = (u32)f2b(v.x) | ((u32)f2b(v.y) << 16);
    o.y = (u32)f2b(v.z) | ((u32)f2b(v.w) << 16);
    ((uint2*)out)[i] = o;
  }
}

// ------- QKV weights: convert + ROW-PERMUTE to head-major output columns -------
// Projection with original weights: out col c uses weight row c, (h=c%16,dk=c/16).
// We want col c' = h*64+dk  =>  W'[c'] = W[(c'&63)*16 + (c'>>6)]. One row per block.
__global__ __launch_bounds__(256) void cvt_w3p(const float* __restrict__ wq,
                                               const float* __restrict__ wk,
                                               const float* __restrict__ wv,
                                               u16* __restrict__ oq,
                                               u16* __restrict__ ok,
                                               u16* __restrict__ ov) {
  const int m = blockIdx.y;
  const float* in = (m == 0) ? wq : ((m == 1) ? wk : wv);
  u16* out = (m == 0) ? oq : ((m == 1) ? ok : ov);
  const int rp = blockIdx.x;                    // c' (output row)
  const int rs = (rp & 63) * 16 + (rp >> 6);    // source row
  const float4 v = ((const float4*)&in[(size_t)rs * DMODEL])[threadIdx.x];
  uint2 o;
  o.x = (u32)f2b(v.x) | ((u32)f2b(v.y) << 16);
  o.y = (u32)f2b(v.z) | ((u32)f2b(v.w) << 16);
  ((uint2*)&out[(size_t)rp * DMODEL])[threadIdx.x] = o;
}

// ---------------- RoPE cos/sin table: tab[s*32+Xi] = (cos, sin) ----------------
__global__ __launch_bounds__(256) void rope_tab_k(const int* __restrict__ tokpos,
                                                  float2* __restrict__ tab) {
  const int i = blockIdx.x * 256 + threadIdx.x; // < SEQ*32
  const int s = i >> 5, Xi = i & 31;
  const float invf = powf(1000.0f, -(float)Xi / 32.0f);
  const float ang = (float)tokpos[s] * invf;
  float sn, cs;
  sincosf(ang, &sn, &cs);
  tab[i] = make_float2(cs, sn);
}

// ---------------- Wo transpose + convert: wot[e][d] = wo[d][e] ----------------
__global__ __launch_bounds__(256) void transpose_wo(const float* __restrict__ wo,
                                                    u16* __restrict__ wot) {
  __shared__ float tile[32][33];
  const int bx = blockIdx.x * 32; // e block
  const int by = blockIdx.y * 32; // d block
  const int tx = threadIdx.x & 31, ty = threadIdx.x >> 5;
  for (int j = ty; j < 32; j += 8)
    tile[j][tx] = wo[(size_t)(by + j) * DMODEL + bx + tx];
  __syncthreads();
  for (int j = ty; j < 32; j += 8)
    wot[(size_t)(bx + j) * DMODEL + by + tx] = f2b(tile[tx][j]);
}

// ---------------- shared GEMM mainloop: C[BM x 128] = A * Bt^T (BK=64) -----------
// R5 core (best measured): single-buffered, 8-chunk XOR swizzle, 0 bank conflicts.
// LDS[row][c] = G[row][c ^ (row&7)] (16B chunks); reads apply the same XOR.
template <int MI>
__device__ __forceinline__ void gemm_core(const u16* __restrict__ A,
                                          const u16* __restrict__ Bt,
                                          int mbase, int nbase,
                                          u16* As, u16* Bs, f32x4 acc[MI][4]) {
  const int t = threadIdx.x;
  const int lane = t & 63, w = t >> 6;
  const int wr = w >> 1, wc = w & 1;
  const int l15 = lane & 15, lg = lane >> 4;
  const int srow = t >> 3;              // 0..31
  const int sch = (t & 7) ^ (srow & 7); // swizzled source chunk
  const int rsw = l15 & 7;              // read-side XOR (row&7 == l15&7)

  for (int kb = 0; kb < DMODEL; kb += 64) {
#pragma unroll
    for (int j = 0; j < MI; ++j)
      gload16(&A[(size_t)(mbase + srow + 32 * j) * DMODEL + kb + sch * 8],
              &As[j * 2048 + t * 8]);
#pragma unroll
    for (int j = 0; j < 4; ++j)
      gload16(&Bt[(size_t)(nbase + srow + 32 * j) * DMODEL + kb + sch * 8],
              &Bs[j * 2048 + t * 8]);
    __syncthreads();
#pragma unroll
    for (int kk = 0; kk < 2; ++kk) {
      bf16x8 af[MI], bfr[4];
#pragma unroll
      for (int mi = 0; mi < MI; ++mi) {
        const int row = wr * (MI * 16) + mi * 16 + l15;
        af[mi] = *(const bf16x8*)&As[row * 64 + (((kk * 4 + lg) ^ rsw) * 8)];
      }
#pragma unroll
      for (int ni = 0; ni < 4; ++ni) {
        const int row = wc * 64 + ni * 16 + l15;
        bfr[ni] = *(const bf16x8*)&Bs[row * 64 + (((kk * 4 + lg) ^ rsw) * 8)];
      }
#pragma unroll
      for (int mi = 0; mi < MI; ++mi)
#pragma unroll
        for (int ni = 0; ni < 4; ++ni)
          acc[mi][ni] =
              __builtin_amdgcn_mfma_f32_16x16x32_bf16(af[mi], bfr[ni], acc[mi][ni], 0, 0, 0);
    }
    __syncthreads();
  }
}

// ---------------- fused QKV projection + RoPE epilogue (head-major cols) --------
// Weights are row-permuted so output col c' = h*64 + dk. RoPE pairs are adjacent
// LANES (shfl_xor 1); Q/K stores are contiguous 32B runs per 16-lane group.
// Q gets 0.125*log2(e) folded in. V^T written as [bh][vd][s] with packed 8B runs.
__global__ __launch_bounds__(256) void gemm_qkv(
    const u16* __restrict__ Xb, const u16* __restrict__ Wqb,
    const u16* __restrict__ Wkb, const u16* __restrict__ Wvb,
    u16* __restrict__ Qb, u16* __restrict__ Kb, u16* __restrict__ Vb,
    const float2* __restrict__ tab) {
  __shared__ __align__(16) u16 As[128 * 64]; // 16 KB
  __shared__ __align__(16) u16 Bs[128 * 64]; // 16 KB

  const int mat = blockIdx.y >> 3;
  const int nbase = (blockIdx.y & 7) * 128;
  const int mbase = blockIdx.x * 128;
  const u16* Bt = (mat == 0) ? Wqb : ((mat == 1) ? Wkb : Wvb);

  f32x4 acc[4][4];
#pragma unroll
  for (int mi = 0; mi < 4; ++mi)
#pragma unroll
    for (int ni = 0; ni < 4; ++ni) {
      f32x4 z = {0.f, 0.f, 0.f, 0.f};
      acc[mi][ni] = z;
    }

  gemm_core<4>(Xb, Bt, mbase, nbase, As, Bs, acc);

  const int t = threadIdx.x;
  const int lane = t & 63, w = t >> 6;
  const int wr = w >> 1, wc = w & 1;
  const int l15 = lane & 15, lg = lane >> 4;

  const int bi = mbase >> 11;                  // batch (tile never crosses)
  const int sbase = (mbase & (SEQ - 1)) + wr * 64;
  const int h = (nbase >> 6) + wc;             // head (head-major cols)
  const int bh = bi * NH + h;

  if (mat == 2) { // V^T [bh][vd][s]: per-lane 4 consecutive s -> 8B packed stores
#pragma unroll
    for (int mi = 0; mi < 4; ++mi) {
      const int s0 = sbase + mi * 16 + lg * 4;
#pragma unroll
      for (int ni = 0; ni < 4; ++ni) {
        const int vd = ni * 16 + l15;
        uint2 pv;
        pv.x = (u32)f2b(acc[mi][ni][0]) | ((u32)f2b(acc[mi][ni][1]) << 16);
        pv.y = (u32)f2b(acc[mi][ni][2]) | ((u32)f2b(acc[mi][ni][3]) << 16);
        *(uint2*)&Vb[((size_t)(bh * DK + vd)) * SEQ + s0] = pv;
      }
    }
  } else { // Q or K: rope across lane pairs, coalesced u32 stores on even lanes
    u16* Ob = (mat == 0) ? Qb : Kb;
    const float qscale = (mat == 0) ? 0.125f * 1.44269504088896f : 1.0f;
    const int odd = l15 & 1;
#pragma unroll
    for (int ni = 0; ni < 4; ++ni) {
      const int Xi = ni * 8 + (l15 >> 1);
#pragma unroll
      for (int mi = 0; mi < 4; ++mi) {
#pragma unroll
        for (int r = 0; r < 4; ++r) {
          const int s = sbase + mi * 16 + lg * 4 + r;
          const float2 ct = tab[(s << 5) + Xi];
          const float val = acc[mi][ni][r];
          const float par = __shfl_xor(val, 1);
          const float x1 = odd ? par : val;
          const float x2 = odd ? val : par;
          const float r1 = (x1 * ct.x - x2 * ct.y) * qscale;
          const float r2 = (x1 * ct.y + x2 * ct.x) * qscale;
          if (!odd) {
            const u32 pk = (u32)f2b(r1) | ((u32)f2b(r2) << 16);
            *(u32*)&Ob[((size_t)(bh * SEQ + s)) * DK + ni * 16 + l15] = pk;
          }
        }
      }
    }
  }
}

// ---------------- flash attention (causal, swapped-operand, in-register softmax) ---
// grid 1024 blocks = 32 q-tiles x 32 heads, remapped so each XCD owns 4 heads
// (KV L2-resident) and heavy q-tiles dispatch first. 256 thr = 4 waves; wave owns
// 16 q rows (q = lane&15 after swapped QK^T -> softmax is lane-local scalars).
// KV tile 64, double-buffered global_load_lds with XOR chunk swizzle.
__global__ __launch_bounds__(256) void flash_attn(
    const u16* __restrict__ Qg, const u16* __restrict__ Kg,
    const u16* __restrict__ VTg, u16* __restrict__ Ag) {
  __shared__ __align__(16) u16 Ks[2][64 * 64];
  __shared__ __align__(16) u16 Vs[2][64 * 64];
  __shared__ __align__(16) u16 Ps[4][16][72];

  // work-id swizzle: id&7 -> XCD slot, 4 heads per XCD, qt descending (heavy first)
  const int id = blockIdx.y * 32 + blockIdx.x;
  const int within = id >> 3;
  const int bh = (id & 7) * 4 + (within & 3);
  const int qt = 31 - (within >> 2);
  const int b = bh >> 4, h = bh & 15;
  const int qbase = qt * 64;

  const size_t hoff = (size_t)bh * SEQ * DK;
  const u16* Qh = Qg + hoff;
  const u16* Kh = Kg + hoff;
  const u16* VTh = VTg + hoff;

  const int t = threadIdx.x;
  const int lane = t & 63, w = t >> 6;
  const int l15 = lane & 15, lg = lane >> 4;
  const int sw = l15 & 7; // read-side XOR

  const int qrow = qbase + w * 16 + l15; // this lane's q row
  const bf16x8 qf0 = *(const bf16x8*)&Qh[(size_t)qrow * DK + lg * 8];
  const bf16x8 qf1 = *(const bf16x8*)&Qh[(size_t)qrow * DK + 32 + lg * 8];

  f32x4 oaccT[4]; // O^T[v = vf*16+lg*4+r][q = l15]
#pragma unroll
  for (int vf = 0; vf < 4; ++vf) {
    f32x4 z = {0.f, 0.f, 0.f, 0.f};
    oaccT[vf] = z;
  }
  float m_r = -1e30f, l_r = 0.0f; // per-lane (per q-row) softmax state

  // staging map: thread t covers LDS bytes [t*16) and [4096 + t*16)
  const int srow = t >> 3;                     // 0..31
  const int sc = ((t & 7) ^ (srow & 7)) * 8;   // swizzled global source chunk

  // prologue: stage tile 0 into buf 0
  gload16(&Kh[(size_t)srow * DK + sc], &Ks[0][t * 8]);
  gload16(&Kh[(size_t)(srow + 32) * DK + sc], &Ks[0][2048 + t * 8]);
  gload16(&VTh[(size_t)srow * SEQ + sc], &Vs[0][t * 8]);
  gload16(&VTh[(size_t)(srow + 32) * SEQ + sc], &Vs[0][2048 + t * 8]);

  for (int kt = 0; kt <= qt; ++kt) {
    const int buf = kt & 1;
    __syncthreads(); // tile kt landed; previous iteration's LDS reads done
    if (kt < qt) {
      const int kb = (kt + 1) * 64;
      gload16(&Kh[(size_t)(kb + srow) * DK + sc], &Ks[buf ^ 1][t * 8]);
      gload16(&Kh[(size_t)(kb + srow + 32) * DK + sc], &Ks[buf ^ 1][2048 + t * 8]);
      gload16(&VTh[(size_t)srow * SEQ + kb + sc], &Vs[buf ^ 1][t * 8]);
      gload16(&VTh[(size_t)(srow + 32) * SEQ + kb + sc], &Vs[buf ^ 1][2048 + t * 8]);
    }
    const int kvbase = kt * 64;

    // S^T = K Q^T : lane holds S[q=qrow][kv = kvbase + f*16 + lg*4 + r]
    f32x4 sT[4];
#pragma unroll
    for (int f = 0; f < 4; ++f) {
      const int row = f * 16 + l15;
      bf16x8 k0 = *(const bf16x8*)&Ks[buf][row * 64 + (lg ^ sw) * 8];
      bf16x8 k1 = *(const bf16x8*)&Ks[buf][row * 64 + ((4 + lg) ^ sw) * 8];
      f32x4 z = {0.f, 0.f, 0.f, 0.f};
      z = __builtin_amdgcn_mfma_f32_16x16x32_bf16(k0, qf0, z, 0, 0, 0);
      z = __builtin_amdgcn_mfma_f32_16x16x32_bf16(k1, qf1, z, 0, 0, 0);
      sT[f] = z;
    }

    if (kt == qt) { // only the diagonal tile needs masking
#pragma unroll
      for (int f = 0; f < 4; ++f)
#pragma unroll
        for (int r = 0; r < 4; ++r) {
          const int kvc = kvbase + f * 16 + lg * 4 + r;
          if (kvc > qrow) sT[f][r] = -1e30f;
        }
    }

    // in-lane row max (16 vals) + 2 cross-lane steps (lg dimension)
    f32x4 mv;
#pragma unroll
    for (int r = 0; r < 4; ++r)
      mv[r] = fmaxf(fmaxf(sT[0][r], sT[1][r]), fmaxf(sT[2][r], sT[3][r]));
    float mx = fmaxf(fmaxf(mv[0], mv[1]), fmaxf(mv[2], mv[3]));
    mx = fmaxf(mx, __shfl_xor(mx, 16));
    mx = fmaxf(mx, __shfl_xor(mx, 32));

    const float mn = fmaxf(m_r, mx);
    const float alpha = exp2f(m_r - mn);
    m_r = mn;
#pragma unroll
    for (int f = 0; f < 4; ++f)
#pragma unroll
      for (int r = 0; r < 4; ++r) sT[f][r] = exp2f(sT[f][r] - mn);

    f32x4 rv;
#pragma unroll
    for (int r = 0; r < 4; ++r) rv[r] = (sT[0][r] + sT[1][r]) + (sT[2][r] + sT[3][r]);
    float rs = (rv[0] + rv[1]) + (rv[2] + rv[3]);
    rs += __shfl_xor(rs, 16);
    rs += __shfl_xor(rs, 32);
    l_r = l_r * alpha + rs;

#pragma unroll
    for (int vf = 0; vf < 4; ++vf)
#pragma unroll
      for (int r = 0; r < 4; ++r) oaccT[vf][r] *= alpha;

    // P row (q=l15) -> LDS: 4x ds_write_b64, contiguous kv runs
#pragma unroll
    for (int f = 0; f < 4; ++f) {
      uint2 pkv;
      pkv.x = (u32)f2b(sT[f][0]) | ((u32)f2b(sT[f][1]) << 16);
      pkv.y = (u32)f2b(sT[f][2]) | ((u32)f2b(sT[f][3]) << 16);
      *(uint2*)&Ps[w][l15][f * 16 + lg * 4] = pkv;
    }

    // O^T += V^T P^T : A = V^T frag, B = P^T frag (2x ds_read_b128 for P)
#pragma unroll
    for (int c = 0; c < 2; ++c) {
      const bf16x8 pb = *(const bf16x8*)&Ps[w][l15][c * 32 + lg * 8];
#pragma unroll
      for (int vf = 0; vf < 4; ++vf) {
        const bf16x8 va =
            *(const bf16x8*)&Vs[buf][(vf * 16 + l15) * 64 + ((c * 4 + lg) ^ sw) * 8];
        oaccT[vf] = __builtin_amdgcn_mfma_f32_16x16x32_bf16(va, pb, oaccT[vf], 0, 0, 0);
      }
    }
  }

  // normalize + write [B,S,D] bf16: d = h*64 + v, packed 4-wide
  const float inv = 1.0f / l_r;
  const size_t base = ((size_t)(b * SEQ + qrow)) * DMODEL + h * DK;
#pragma unroll
  for (int vf = 0; vf < 4; ++vf) {
    uint2 ov;
    ov.x = (u32)f2b(oaccT[vf][0] * inv) | ((u32)f2b(oaccT[vf][1] * inv) << 16);
    ov.y = (u32)f2b(oaccT[vf][2] * inv) | ((u32)f2b(oaccT[vf][3] * inv) << 16);
    *(uint2*)&Ag[base + vf * 16 + lg * 4] = ov;
  }
}

// ---------------- output projection: d_out = Ab * Wot^T (fp32 out) ----------------
// 64x128 tile (MI=2), grid (64, 8) = 512 blocks (2/CU).
__global__ __launch_bounds__(256) void gemm_out(const u16* __restrict__ Ab,
                                                const u16* __restrict__ Wotb,
                                                float* __restrict__ Co) {
  __shared__ __align__(16) u16 As[64 * 64];  // 8 KB
  __shared__ __align__(16) u16 Bs[128 * 64]; // 16 KB
  const int mbase = blockIdx.x * 64, nbase = blockIdx.y * 128;

  f32x4 acc[2][4];
#pragma unroll
  for (int mi = 0; mi < 2; ++mi)
#pragma unroll
    for (int ni = 0; ni < 4; ++ni) {
      f32x4 z = {0.f, 0.f, 0.f, 0.f};
      acc[mi][ni] = z;
    }

  gemm_core<2>(Ab, Wotb, mbase, nbase, As, Bs, acc);

  const int t = threadIdx.x;
  const int lane = t & 63, w = t >> 6;
  const int wr = w >> 1, wc = w & 1;
  const int l15 = lane & 15, lg = lane >> 4;
#pragma unroll
  for (int mi = 0; mi < 2; ++mi) {
#pragma unroll
    for (int r = 0; r < 4; ++r) {
      const int row = mbase + wr * 32 + mi * 16 + lg * 4 + r;
#pragma unroll
      for (int ni = 0; ni < 4; ++ni) {
        const int c = nbase + wc * 64 + ni * 16 + l15;
        Co[(size_t)row * DMODEL + c] = acc[mi][ni][r];
      }
    }
  }
}

extern "C" void kernel_launch(void* const* d_in, const int* in_sizes, int n_in,
                              void* d_out, int out_size, void* d_ws, size_t ws_size,
                              hipStream_t stream) {
  const float* X = (const float*)d_in[0];
  const float* Wq = (const float*)d_in[1];
  const float* Wk = (const float*)d_in[2];
  const float* Wv = (const float*)d_in[3];
  const float* Wo = (const float*)d_in[4];
  const int* tokpos = (const int*)d_in[5];
  float* out = (float*)d_out;

  u16* p = (u16*)d_ws;
  u16* Xb = p;   p += (size_t)MTOT * DMODEL;        // 4M el
  u16* Wqb = p;  p += (size_t)DMODEL * DMODEL;      // 1M el
  u16* Wkb = p;  p += (size_t)DMODEL * DMODEL;
  u16* Wvb = p;  p += (size_t)DMODEL * DMODEL;
  u16* Wotb = p; p += (size_t)DMODEL * DMODEL;
  u16* Qb = p;   p += (size_t)BATCH * NH * SEQ * DK; // 4M el
  u16* Kb = p;   p += (size_t)BATCH * NH * SEQ * DK;
  u16* Vb = p;   p += (size_t)BATCH * NH * SEQ * DK; // holds V^T [bh][vd][s]
  float2* tab = (float2*)(p + 512);                  // 512 KB rope table (aligned)
  u16* Ab = Xb; // X is dead after QKV projection; reuse for attention output

  cvt_bf16<<<4096, 256, 0, stream>>>(X, Xb, (MTOT * DMODEL) / 4);
  cvt_w3p<<<dim3(1024, 3), 256, 0, stream>>>(Wq, Wk, Wv, Wqb, Wkb, Wvb);
  transpose_wo<<<dim3(32, 32), 256, 0, stream>>>(Wo, Wotb);
  rope_tab_k<<<(SEQ * 32) / 256, 256, 0, stream>>>(tokpos, tab);

  gemm_qkv<<<dim3(32, 24), 256, 0, stream>>>(Xb, Wqb, Wkb, Wvb, Qb, Kb, Vb, tab);
  flash_attn<<<dim3(32, 32), 256, 0, stream>>>(Qb, Kb, Vb, Ab);
  gemm_out<<<dim3(64, 8), 256, 0, stream>>>(Ab, Wotb, out);
}